// Round 15
// baseline (920.877 us; speedup 1.0000x reference)
//
#include <hip/hip_runtime.h>
#include <math.h>

#define M_TOTAL 8192
#define N_RFF   4096
#define K_DIM   512
#define TOPK    409

#define BMs 64
#define BNs 64
#define BKs 32

// ---------------------------------------------------------------------------
// GEMM: theta[r][c] = SINGLE ascending-k f32 fmaf chain over k=0..511
// (OpenBLAS large-Q / Eigen kc>=512 / XLA-CPU structure: one accumulator
// per C element, strict ascending k, fused multiply-add).
// s = theta + b (f32); z = (float)cos((double)s) * f32(SCALE)
// [correctly-rounded f32 cos == glibc cosf (<=0.5009 ulp) == XLA libm path].
// ---------------------------------------------------------------------------
__global__ __launch_bounds__(256) void rff_gemm_chain(
    const float* __restrict__ x, const float* __restrict__ W,
    const float* __restrict__ bias, float* __restrict__ zbuf,
    int m0, int rows)
{
    __shared__ float As[BKs][BMs + 1];
    __shared__ float Bs[BKs][BNs + 1];

    const int tid = threadIdx.x;
    const int bm = blockIdx.y * BMs, bn = blockIdx.x * BNs;
    const int tx = tid & 15, ty = tid >> 4;

    float acc[4][4];
    #pragma unroll
    for (int i = 0; i < 4; ++i)
        #pragma unroll
        for (int j = 0; j < 4; ++j) acc[i][j] = 0.0f;

    for (int kt = 0; kt < K_DIM; kt += BKs) {
        #pragma unroll
        for (int t = 0; t < 8; ++t) {
            const int idx = t * 256 + tid;      // 0..2047, each once
            const int r = idx >> 5, k = idx & 31;
            int gr = m0 + bm + r;               // clamped read; write guarded
            if (gr > M_TOTAL - 1) gr = M_TOTAL - 1;
            As[k][r] = x[(size_t)gr * K_DIM + kt + k];
            Bs[k][r] = W[(size_t)(bn + r) * K_DIM + kt + k];
        }
        __syncthreads();

        // strict ascending-k, one dependent fmaf chain per C element
        #pragma unroll
        for (int k = 0; k < BKs; ++k) {
            float a[4], b[4];
            #pragma unroll
            for (int i = 0; i < 4; ++i) a[i] = As[k][ty * 4 + i];
            #pragma unroll
            for (int j = 0; j < 4; ++j) b[j] = Bs[k][tx * 4 + j];
            #pragma unroll
            for (int i = 0; i < 4; ++i)
                #pragma unroll
                for (int j = 0; j < 4; ++j)
                    acc[i][j] = fmaf(a[i], b[j], acc[i][j]);
        }
        __syncthreads();
    }

    const float SC32 = 0.0220970869f;   // f32(sqrt(2/4096)) = 0x3CB504F3

    #pragma unroll
    for (int i = 0; i < 4; ++i) {
        const int rloc = bm + ty * 4 + i;
        if (rloc < rows) {
            float* zr = zbuf + (size_t)rloc * N_RFF + bn;
            #pragma unroll
            for (int j = 0; j < 4; ++j) {
                const int c = tx * 4 + j;
                const float s = acc[i][j] + bias[bn + c];   // f32 bias add
                zr[c] = (float)cos((double)s) * SC32;       // CR f32 cos, f32 mul
            }
        }
    }
}

// ---------------------------------------------------------------------------
// Per-row exact top-K on f32 keys |z|, smallest-index tie-break
// (stable argsort-desc / lax.top_k semantics).
// ---------------------------------------------------------------------------
__global__ __launch_bounds__(256) void topk_select(
    const float* __restrict__ zbuf, float* __restrict__ out, int m0)
{
    const int row = blockIdx.x;
    const int tid = threadIdx.x;
    const float* z = zbuf + (size_t)row * N_RFF;

    float v[16];
    unsigned int key[16];
    #pragma unroll
    for (int i = 0; i < 16; ++i) {
        v[i]   = z[tid + i * 256];
        key[i] = __float_as_uint(fabsf(v[i]));
    }

    __shared__ unsigned int hist[256];
    __shared__ unsigned int s_pref;
    __shared__ int s_k;
    __shared__ int tielist[64];
    __shared__ int tiecnt;
    __shared__ unsigned int keepbits[N_RFF / 32];

    if (tid == 0) tiecnt = 0;
    if (tid < N_RFF / 32) keepbits[tid] = 0u;

    unsigned int prefix = 0u;
    int kneed = TOPK;

    for (int shift = 24; shift >= 0; shift -= 8) {
        hist[tid] = 0u;
        __syncthreads();
        const unsigned int pmask = (shift == 24) ? 0u : (0xFFFFFFFFu << (shift + 8));
        #pragma unroll
        for (int i = 0; i < 16; ++i)
            if ((key[i] & pmask) == prefix)
                atomicAdd(&hist[(key[i] >> shift) & 255u], 1u);
        __syncthreads();
        if (tid == 0) {
            unsigned int accum = 0; int d = 255;
            for (; d >= 0; --d) {
                const unsigned int c = hist[d];
                if (accum + c >= (unsigned)kneed) break;
                accum += c;
            }
            if (d < 0) d = 0;
            s_pref = prefix | ((unsigned int)d << shift);
            s_k = kneed - (int)accum;
        }
        __syncthreads();
        prefix = s_pref; kneed = s_k;
        __syncthreads();
    }

    const unsigned int thr = prefix;

    #pragma unroll
    for (int i = 0; i < 16; ++i) {
        if (key[i] == thr) {
            const int p = atomicAdd(&tiecnt, 1);
            if (p < 64) tielist[p] = tid + i * 256;
        }
    }
    __syncthreads();

    if (tid == 0) {
        int n = tiecnt; if (n > 64) n = 64;
        for (int a = 1; a < n; ++a) {
            const int vi = tielist[a];
            int b2 = a - 1;
            while (b2 >= 0 && tielist[b2] > vi) { tielist[b2 + 1] = tielist[b2]; --b2; }
            tielist[b2 + 1] = vi;
        }
        int t = kneed; if (t > n) t = n;
        for (int a = 0; a < t; ++a) {
            const int idx = tielist[a];
            keepbits[idx >> 5] |= (1u << (idx & 31));
        }
    }
    __syncthreads();

    float* orow = out + (size_t)(m0 + row) * N_RFF;
    #pragma unroll
    for (int i = 0; i < 16; ++i) {
        const int idx = tid + i * 256;
        const bool keep = (key[i] > thr) ||
                          (key[i] == thr && ((keepbits[idx >> 5] >> (idx & 31)) & 1u));
        orow[idx] = keep ? v[i] : 0.0f;
    }
}

// ---------------------------------------------------------------------------
extern "C" void kernel_launch(void* const* d_in, const int* in_sizes, int n_in,
                              void* d_out, int out_size, void* d_ws, size_t ws_size,
                              hipStream_t stream)
{
    const float* x    = (const float*)d_in[0];
    const float* W    = (const float*)d_in[1];
    const float* bias = (const float*)d_in[2];
    float* out  = (float*)d_out;
    float* zbuf = (float*)d_ws;

    const size_t row_bytes = (size_t)N_RFF * sizeof(float);
    const size_t maxrows   = row_bytes ? (ws_size / row_bytes) : 0;

    int chunk = (maxrows >= (size_t)M_TOTAL) ? M_TOTAL : (int)maxrows;
    if (chunk < 1) chunk = 1;

    for (int m0 = 0; m0 < M_TOTAL; m0 += chunk) {
        int rows = M_TOTAL - m0;
        if (rows > chunk) rows = chunk;
        dim3 gg(N_RFF / BNs, (rows + BMs - 1) / BMs);
        hipLaunchKernelGGL(rff_gemm_chain, gg, dim3(256), 0, stream,
                           x, W, bias, zbuf, m0, rows);
        hipLaunchKernelGGL(topk_select, dim3(rows), dim3(256), 0, stream,
                           zbuf, out, m0);
    }
}

// Round 16
// 693.067 us; speedup vs baseline: 1.3287x; 1.3287x over previous
//
#include <hip/hip_runtime.h>
#include <math.h>

#define M_TOTAL 8192
#define N_RFF   4096
#define K_DIM   512
#define TOPK    409

#define BM 128
#define BN 128
#define BK 16
#define LDSV (BM + 4)   // 132 floats = 528 B row stride (16B-aligned)

// ---------------------------------------------------------------------------
// GEMM: theta[r][c] = SINGLE ascending-k f32 fmaf chain over k=0..511
// (bit-frozen reference semantics). 128x128 tile, 8x8 acc/thread (4+4 split).
// s = theta + b (f32); z = (float)cos((double)s) * f32(SCALE).
// ---------------------------------------------------------------------------
__global__ __launch_bounds__(256) void rff_gemm_chain(
    const float* __restrict__ x, const float* __restrict__ W,
    const float* __restrict__ bias, float* __restrict__ zbuf,
    int m0, int rows)
{
    __shared__ float As[BK][LDSV];
    __shared__ float Bs[BK][LDSV];

    const int tid = threadIdx.x;
    const int bm = blockIdx.y * BM, bn = blockIdx.x * BN;
    const int tx = tid & 15, ty = tid >> 4;

    float acc[8][8];
    #pragma unroll
    for (int i = 0; i < 8; ++i)
        #pragma unroll
        for (int j = 0; j < 8; ++j) acc[i][j] = 0.0f;

    for (int kt = 0; kt < K_DIM; kt += BK) {
        // stage A,B tiles: 128 rows x 16 k each, float4 loads (4 k's per slot)
        #pragma unroll
        for (int it = 0; it < 2; ++it) {
            const int i = tid + it * 256;     // 0..511
            const int r = i >> 2;             // 0..127
            const int q = i & 3;              // k-quad
            int gr = m0 + bm + r;             // clamped read; write guarded
            if (gr > M_TOTAL - 1) gr = M_TOTAL - 1;
            const float4 va = *(const float4*)(x + (size_t)gr * K_DIM + kt + q * 4);
            As[q*4+0][r] = va.x;  As[q*4+1][r] = va.y;
            As[q*4+2][r] = va.z;  As[q*4+3][r] = va.w;
            const float4 vb = *(const float4*)(W + (size_t)(bn + r) * K_DIM + kt + q * 4);
            Bs[q*4+0][r] = vb.x;  Bs[q*4+1][r] = vb.y;
            Bs[q*4+2][r] = vb.z;  Bs[q*4+3][r] = vb.w;
        }
        __syncthreads();

        // strict ascending-k; each acc[i][j] is one dependent fmaf chain
        #pragma unroll
        for (int k = 0; k < BK; ++k) {
            float a[8], b[8];
            #pragma unroll
            for (int i = 0; i < 4; ++i) {
                a[i]     = As[k][ty * 4 + i];
                a[4 + i] = As[k][64 + ty * 4 + i];
            }
            #pragma unroll
            for (int j = 0; j < 4; ++j) {
                b[j]     = Bs[k][tx * 4 + j];
                b[4 + j] = Bs[k][64 + tx * 4 + j];
            }
            #pragma unroll
            for (int i = 0; i < 8; ++i)
                #pragma unroll
                for (int j = 0; j < 8; ++j)
                    acc[i][j] = fmaf(a[i], b[j], acc[i][j]);
        }
        __syncthreads();
    }

    const float SC32 = 0.0220970869f;   // f32(sqrt(2/4096)) = 0x3CB504F3

    #pragma unroll
    for (int i = 0; i < 8; ++i) {
        const int rloc = bm + ((i < 4) ? (ty * 4 + i) : (64 + ty * 4 + (i - 4)));
        if (rloc < rows) {
            float* zr = zbuf + (size_t)rloc * N_RFF + bn;
            #pragma unroll
            for (int j = 0; j < 8; ++j) {
                const int c = (j < 4) ? (tx * 4 + j) : (64 + tx * 4 + (j - 4));
                const float s = acc[i][j] + bias[bn + c];   // f32 bias add
                zr[c] = (float)cos((double)s) * SC32;       // CR f32 cos, f32 mul
            }
        }
    }
}

// ---------------------------------------------------------------------------
// Per-row exact top-K on f32 keys |z|, smallest-index tie-break
// (stable argsort-desc / lax.top_k semantics).
// ---------------------------------------------------------------------------
__global__ __launch_bounds__(256) void topk_select(
    const float* __restrict__ zbuf, float* __restrict__ out, int m0)
{
    const int row = blockIdx.x;
    const int tid = threadIdx.x;
    const float* z = zbuf + (size_t)row * N_RFF;

    float v[16];
    unsigned int key[16];
    #pragma unroll
    for (int i = 0; i < 16; ++i) {
        v[i]   = z[tid + i * 256];
        key[i] = __float_as_uint(fabsf(v[i]));
    }

    __shared__ unsigned int hist[256];
    __shared__ unsigned int s_pref;
    __shared__ int s_k;
    __shared__ int tielist[64];
    __shared__ int tiecnt;
    __shared__ unsigned int keepbits[N_RFF / 32];

    if (tid == 0) tiecnt = 0;
    if (tid < N_RFF / 32) keepbits[tid] = 0u;

    unsigned int prefix = 0u;
    int kneed = TOPK;

    for (int shift = 24; shift >= 0; shift -= 8) {
        hist[tid] = 0u;
        __syncthreads();
        const unsigned int pmask = (shift == 24) ? 0u : (0xFFFFFFFFu << (shift + 8));
        #pragma unroll
        for (int i = 0; i < 16; ++i)
            if ((key[i] & pmask) == prefix)
                atomicAdd(&hist[(key[i] >> shift) & 255u], 1u);
        __syncthreads();
        if (tid == 0) {
            unsigned int accum = 0; int d = 255;
            for (; d >= 0; --d) {
                const unsigned int c = hist[d];
                if (accum + c >= (unsigned)kneed) break;
                accum += c;
            }
            if (d < 0) d = 0;
            s_pref = prefix | ((unsigned int)d << shift);
            s_k = kneed - (int)accum;
        }
        __syncthreads();
        prefix = s_pref; kneed = s_k;
        __syncthreads();
    }

    const unsigned int thr = prefix;

    #pragma unroll
    for (int i = 0; i < 16; ++i) {
        if (key[i] == thr) {
            const int p = atomicAdd(&tiecnt, 1);
            if (p < 64) tielist[p] = tid + i * 256;
        }
    }
    __syncthreads();

    if (tid == 0) {
        int n = tiecnt; if (n > 64) n = 64;
        for (int a = 1; a < n; ++a) {
            const int vi = tielist[a];
            int b2 = a - 1;
            while (b2 >= 0 && tielist[b2] > vi) { tielist[b2 + 1] = tielist[b2]; --b2; }
            tielist[b2 + 1] = vi;
        }
        int t = kneed; if (t > n) t = n;
        for (int a = 0; a < t; ++a) {
            const int idx = tielist[a];
            keepbits[idx >> 5] |= (1u << (idx & 31));
        }
    }
    __syncthreads();

    float* orow = out + (size_t)(m0 + row) * N_RFF;
    #pragma unroll
    for (int i = 0; i < 16; ++i) {
        const int idx = tid + i * 256;
        const bool keep = (key[i] > thr) ||
                          (key[i] == thr && ((keepbits[idx >> 5] >> (idx & 31)) & 1u));
        orow[idx] = keep ? v[i] : 0.0f;
    }
}

// ---------------------------------------------------------------------------
extern "C" void kernel_launch(void* const* d_in, const int* in_sizes, int n_in,
                              void* d_out, int out_size, void* d_ws, size_t ws_size,
                              hipStream_t stream)
{
    const float* x    = (const float*)d_in[0];
    const float* W    = (const float*)d_in[1];
    const float* bias = (const float*)d_in[2];
    float* out  = (float*)d_out;
    float* zbuf = (float*)d_ws;

    const size_t row_bytes = (size_t)N_RFF * sizeof(float);
    const size_t maxrows   = row_bytes ? (ws_size / row_bytes) : 0;

    int chunk = (maxrows >= (size_t)M_TOTAL) ? M_TOTAL : (int)maxrows;
    if (chunk < 1) chunk = 1;

    for (int m0 = 0; m0 < M_TOTAL; m0 += chunk) {
        int rows = M_TOTAL - m0;
        if (rows > chunk) rows = chunk;
        dim3 gg(N_RFF / BN, (rows + BM - 1) / BM);
        hipLaunchKernelGGL(rff_gemm_chain, gg, dim3(256), 0, stream,
                           x, W, bias, zbuf, m0, rows);
        hipLaunchKernelGGL(topk_select, dim3(rows), dim3(256), 0, stream,
                           zbuf, out, m0);
    }
}